// Round 3
// baseline (325.316 us; speedup 1.0000x reference)
//
#include <hip/hip_runtime.h>
#include <math.h>

static constexpr int Bb = 4;
static constexpr int Nn = 512;
static constexpr int Dd = 1024;
static constexpr int Ee = 8;
static constexpr int Hh = 4096;
static constexpr float CAP = 4.0f;   // float(int(1.0 * B))
static constexpr float EPS = 1e-6f;

static constexpr int P1S = 32;   // ffn1 k-splits (depth 32)
static constexpr int P2S = 32;   // ffn2 k-splits (depth 128)

// ws layout (float offsets):
//   [0,256)             bmask (int, one per gate block; fully written -> no memset)
//   [256,288)           gate0
//   [320,352)           gs
//   [352,360)           tail counters (int[8], zeroed by N1 gate block 0)
//   [512,131584)        hT[32][4096]   (token-major)
//   [132096,4326400)    p1[32*32][4096]
//   [4326400,5374976)   p2[32*32][1024]

// =====================================================================
// N1: blocks [0,256) ffn1 k-split GEMM (stages x directly)
//     blocks [256,512) gating (8 tokens/block) + zero own dead out rows
//                      + (block 256) zero tail counters
// =====================================================================
__global__ __launch_bounds__(256) void k1_gate_ffn1(
    const float* __restrict__ x, const float* __restrict__ wg,
    const float* __restrict__ bg, const float* __restrict__ w1,
    int* __restrict__ bmask, float* __restrict__ gate0,
    float* __restrict__ p1, float* __restrict__ out,
    int* __restrict__ counters)
{
    __shared__ float smem[8 * 1028 + 16];   // 32.96 KB (gate); ffn1 uses first 1024
    const int blk = blockIdx.x;
    const int tid = threadIdx.x;

    if (blk < 256) {
        // ---- ffn1 partial GEMM: h-chunk hc (512 wide), k-chunk ks (32 deep) ----
        const int hc = blk & 7, ks = blk >> 3, k0 = ks * 32;
        {   // stage x[32 live tokens][k0..k0+32) -> smem as [k][t]
            const int t = tid >> 3, q = tid & 7;
            const int row = (t >> 3) * Nn + (t & 7);       // token t = b*8+n
            float4 v = *(const float4*)(x + (size_t)row * Dd + k0 + q * 4);
            smem[(q * 4 + 0) * 32 + t] = v.x;
            smem[(q * 4 + 1) * 32 + t] = v.y;
            smem[(q * 4 + 2) * 32 + t] = v.z;
            smem[(q * 4 + 3) * 32 + t] = v.w;
        }
        __syncthreads();
        const int h = hc * 512 + tid * 2;
        const float* wp = w1 + (size_t)k0 * Hh + h;        // expert 0: w1[d][h]
        float2 acc[32];
#pragma unroll
        for (int t = 0; t < 32; ++t) acc[t] = make_float2(0.f, 0.f);
#pragma unroll
        for (int half = 0; half < 2; ++half) {
            float2 wbuf[16];
#pragma unroll
            for (int kk = 0; kk < 16; ++kk)
                wbuf[kk] = *(const float2*)(wp + (size_t)(half * 16 + kk) * Hh);
#pragma unroll
            for (int kk = 0; kk < 16; ++kk) {
                const float4* xrow = (const float4*)(smem + (half * 16 + kk) * 32);
                const float2 w = wbuf[kk];
#pragma unroll
                for (int t4 = 0; t4 < 8; ++t4) {
                    float4 xv = xrow[t4];
                    acc[t4 * 4 + 0].x = fmaf(xv.x, w.x, acc[t4 * 4 + 0].x);
                    acc[t4 * 4 + 0].y = fmaf(xv.x, w.y, acc[t4 * 4 + 0].y);
                    acc[t4 * 4 + 1].x = fmaf(xv.y, w.x, acc[t4 * 4 + 1].x);
                    acc[t4 * 4 + 1].y = fmaf(xv.y, w.y, acc[t4 * 4 + 1].y);
                    acc[t4 * 4 + 2].x = fmaf(xv.z, w.x, acc[t4 * 4 + 2].x);
                    acc[t4 * 4 + 2].y = fmaf(xv.z, w.y, acc[t4 * 4 + 2].y);
                    acc[t4 * 4 + 3].x = fmaf(xv.w, w.x, acc[t4 * 4 + 3].x);
                    acc[t4 * 4 + 3].y = fmaf(xv.w, w.y, acc[t4 * 4 + 3].y);
                }
            }
        }
        float* o = p1 + ((size_t)ks * 32) * Hh + h;
#pragma unroll
        for (int t = 0; t < 32; ++t) { *(float2*)o = acc[t]; o += Hh; }
    } else {
        // ---- gating + zeroing: block g handles tokens g*8 .. g*8+7 ----
        const int g = blk - 256;
        if (g == 0 && tid < 8) counters[tid] = 0;
        {   // zero this block's dead out rows (n >= 8)
            const float4 zero4 = make_float4(0.f, 0.f, 0.f, 0.f);
#pragma unroll
            for (int r = 0; r < 8; ++r) {
                const int tok = g * 8 + r;
                if ((tok & (Nn - 1)) >= 8)
                    *(float4*)(out + (size_t)tok * Dd + tid * 4) = zero4;
            }
        }
        for (int i = tid; i < Dd * Ee; i += 256)
            smem[(i & 7) * 1028 + (i >> 3)] = wg[i];       // wg[d][e] -> [e][d] padded
        int* bb = (int*)&smem[8224];
        __syncthreads();
        const int wave = tid >> 6, lane = tid & 63;
        for (int j = 0; j < 2; ++j) {
            const int sub = wave + 4 * j;                  // 0..7
            const int tok = g * 8 + sub;
            const float* xr = x + (size_t)tok * Dd;
            float acc[Ee];
#pragma unroll
            for (int e = 0; e < Ee; ++e) acc[e] = 0.f;
#pragma unroll
            for (int jj = 0; jj < 4; ++jj) {
                const int d0 = jj * 256 + lane * 4;
                float4 xv = *(const float4*)(xr + d0);
#pragma unroll
                for (int e = 0; e < Ee; ++e) {
                    float4 wv = *(const float4*)(&smem[e * 1028 + d0]);
                    acc[e] = fmaf(xv.x, wv.x, acc[e]);
                    acc[e] = fmaf(xv.y, wv.y, acc[e]);
                    acc[e] = fmaf(xv.z, wv.z, acc[e]);
                    acc[e] = fmaf(xv.w, wv.w, acc[e]);
                }
            }
#pragma unroll
            for (int e = 0; e < Ee; ++e) {
                float v = acc[e];
#pragma unroll
                for (int off = 32; off > 0; off >>= 1) v += __shfl_xor(v, off, 64);
                acc[e] = v + bg[e];
            }
            if (lane == 0) {
                int best = 0;
                float bv = acc[0];
#pragma unroll
                for (int e = 1; e < Ee; ++e)
                    if (acc[e] > bv) { bv = acc[e]; best = e; }   // strict > = jnp.argmax
                bb[sub] = 1 << best;
                const int n = tok & (Nn - 1);
                const int b = tok >> 9;
                if (n < 8) {
                    float m = acc[0];
#pragma unroll
                    for (int e = 1; e < Ee; ++e) m = fmaxf(m, acc[e]);
                    float s = 0.f;
#pragma unroll
                    for (int e = 0; e < Ee; ++e) s += expf(acc[e] - m);
                    gate0[b * 8 + n] = expf(acc[0] - m) / s;   // softmax prob of expert 0
                }
            }
        }
        __syncthreads();
        if (tid == 0) {
            int m = 0;
#pragma unroll
            for (int i = 0; i < 8; ++i) m |= bb[i];
            bmask[g] = m;
        }
    }
}

// =====================================================================
// N2: blocks [0,256) reduce p1 + bias + exact GELU -> hT[t][hh]
//     block 256: lane-parallel gate_scores + loss
// =====================================================================
__global__ __launch_bounds__(128) void k2_gelu_score(
    const float* __restrict__ p1, const float* __restrict__ b1,
    float* __restrict__ hT, const int* __restrict__ bmask,
    const float* __restrict__ gate0, float* __restrict__ gs,
    float* __restrict__ loss_out)
{
    const int blk = blockIdx.x, tid = threadIdx.x;
    if (blk < 256) {
        const int idx = blk * 128 + tid;              // 0..32767 (float4 granularity)
        const int hh0 = (idx << 2) & (Hh - 1);
        const int t = idx >> 10;
        float4 s = *(const float4*)(b1 + hh0);        // expert 0: b1[0][hh]
#pragma unroll
        for (int q = 0; q < P1S; ++q) {
            float4 v = *(const float4*)(p1 + ((size_t)(q * 32 + t)) * Hh + hh0);
            s.x += v.x; s.y += v.y; s.z += v.z; s.w += v.w;
        }
        const float c = 0.70710678118654752440f;
        float4 r;
        r.x = 0.5f * s.x * (1.f + erff(s.x * c));
        r.y = 0.5f * s.y * (1.f + erff(s.y * c));
        r.z = 0.5f * s.z * (1.f + erff(s.z * c));
        r.w = 0.5f * s.w * (1.f + erff(s.w * c));
        *(float4*)(hT + (size_t)t * Hh + hh0) = r;    // coalesced, t-major
    } else if (tid < 64) {
        const int l = tid;
        int m0 = bmask[l], m1 = bmask[64 + l], m2 = bmask[128 + l], m3 = bmask[192 + l];
#pragma unroll
        for (int off = 32; off > 0; off >>= 1) {
            m0 |= __shfl_xor(m0, off, 64);
            m1 |= __shfl_xor(m1, off, 64);
            m2 |= __shfl_xor(m2, off, 64);
            m3 |= __shfl_xor(m3, off, 64);
        }
        float gm = 0.f;
        if (l < 32) {
            const int b = l >> 3, n = l & 7;
            const int sm = (b == 0) ? m0 : (b == 1) ? m1 : (b == 2) ? m2 : m3;
            if ((sm >> n) & 1) gm = gate0[l];
        }
        float den = gm + __shfl_xor(gm, 8, 64);
        den += __shfl_xor(den, 16, 64);
        float gsv = 0.f;
        if (l < 32) { gsv = gm / (den + EPS) * CAP; gs[l] = gsv; }
        float impn = gsv + __shfl_xor(gsv, 8, 64); impn += __shfl_xor(impn, 16, 64);
        float ldv = (gsv > 0.f) ? 1.f : 0.f;
        float ldn = ldv + __shfl_xor(ldv, 8, 64); ldn += __shfl_xor(ldn, 16, 64);
        float si = gsv, sl = ldv;
#pragma unroll
        for (int off = 32; off > 0; off >>= 1) {
            si += __shfl_xor(si, off, 64);
            sl += __shfl_xor(sl, off, 64);
        }
        const float M = (float)(Nn * Ee);
        const float mi = si / M, ml = sl / M;
        float di = (l < 8) ? (impn - mi) * (impn - mi) : 0.f;
        float dl = (l < 8) ? (ldn - ml) * (ldn - ml) : 0.f;
#pragma unroll
        for (int off = 32; off > 0; off >>= 1) {
            di += __shfl_xor(di, off, 64);
            dl += __shfl_xor(dl, off, 64);
        }
        if (l == 0) {
            di += (M - 8.f) * mi * mi;
            dl += (M - 8.f) * ml * ml;
            const float vi = di / (M - 1.f), vl = dl / (M - 1.f);
            *loss_out = vi / (mi * mi + 1e-10f) + vl / (ml * ml + 1e-10f);
        }
    }
}

// =====================================================================
// N3: ffn2 GEMM, grid (8 d-chunks of 128, 32 k-splits of 128), 128 thr.
//     Last block per d-chunk (fence+counter) reduces the 32 partials,
//     applies bias + gate scale, writes the 32 live out rows. (old K4)
// =====================================================================
__global__ __launch_bounds__(128) void k3_ffn2(
    const float* __restrict__ w2, const float* __restrict__ hT,
    float* __restrict__ p2, const float* __restrict__ b2,
    const float* __restrict__ gs, float* __restrict__ out,
    int* __restrict__ counters)
{
    __shared__ float smem[128 * 32];     // [k][t]
    const int tid = threadIdx.x;
    const int ky = blockIdx.y;           // k-split 0..31
    {
        const int t = tid & 31, kq = tid >> 5;    // kq 0..3 (32 k each)
        const float* src = hT + (size_t)t * Hh + ky * 128 + kq * 32;
#pragma unroll
        for (int c = 0; c < 8; ++c) {
            float4 v = *(const float4*)(src + c * 4);
            smem[(kq * 32 + c * 4 + 0) * 32 + t] = v.x;
            smem[(kq * 32 + c * 4 + 1) * 32 + t] = v.y;
            smem[(kq * 32 + c * 4 + 2) * 32 + t] = v.z;
            smem[(kq * 32 + c * 4 + 3) * 32 + t] = v.w;
        }
    }
    __syncthreads();
    const int d = blockIdx.x * 128 + tid;
    const int k0 = ky * 128;
    const float* wp = w2 + (size_t)k0 * Dd + d;   // expert 0: w2[h][d]
    float acc[32];
#pragma unroll
    for (int t = 0; t < 32; ++t) acc[t] = 0.f;
#pragma unroll
    for (int q = 0; q < 8; ++q) {
        float wbuf[16];
#pragma unroll
        for (int kk = 0; kk < 16; ++kk)
            wbuf[kk] = wp[(size_t)(q * 16 + kk) * Dd];
#pragma unroll
        for (int kk = 0; kk < 16; ++kk) {
            const float4* xrow = (const float4*)(smem + (q * 16 + kk) * 32);
            const float w = wbuf[kk];
#pragma unroll
            for (int t4 = 0; t4 < 8; ++t4) {
                float4 xv = xrow[t4];
                acc[t4 * 4 + 0] = fmaf(xv.x, w, acc[t4 * 4 + 0]);
                acc[t4 * 4 + 1] = fmaf(xv.y, w, acc[t4 * 4 + 1]);
                acc[t4 * 4 + 2] = fmaf(xv.z, w, acc[t4 * 4 + 2]);
                acc[t4 * 4 + 3] = fmaf(xv.w, w, acc[t4 * 4 + 3]);
            }
        }
    }
    float* o = p2 + ((size_t)ky * 32) * Dd + d;
#pragma unroll
    for (int t = 0; t < 32; ++t) { *o = acc[t]; o += Dd; }

    // ---- last-arriver tail: reduce partials for this d-chunk -> out ----
    __threadfence();                              // release partial stores
    __shared__ int lastFlag;
    if (tid == 0)
        lastFlag = (atomicAdd(&counters[blockIdx.x], 1) == P2S - 1);
    __syncthreads();
    if (!lastFlag) return;
    __threadfence();                              // acquire others' stores
    const float bv = b2[d];
    for (int t = 0; t < 32; ++t) {
        float a = 0.f;
        const float* p = p2 + (size_t)t * Dd + d;
#pragma unroll 8
        for (int s = 0; s < P2S; ++s) {           // same order as old K4
            a += *p;
            p += (size_t)32 * Dd;
        }
        const int b = t >> 3, n = t & 7;
        out[((size_t)(b * Nn + n)) * Dd + d] = gs[t] * (a + bv);
    }
}

extern "C" void kernel_launch(void* const* d_in, const int* in_sizes, int n_in,
                              void* d_out, int out_size, void* d_ws, size_t ws_size,
                              hipStream_t stream) {
    const float* x  = (const float*)d_in[0];
    const float* wg = (const float*)d_in[1];
    const float* bg = (const float*)d_in[2];
    const float* w1 = (const float*)d_in[3];
    const float* b1 = (const float*)d_in[4];
    const float* w2 = (const float*)d_in[5];
    const float* b2 = (const float*)d_in[6];
    float* out = (float*)d_out;
    float* wsf = (float*)d_ws;

    int*   bmask    = (int*)d_ws;
    float* gate0    = wsf + 256;
    float* gs       = wsf + 320;
    int*   counters = ((int*)d_ws) + 352;
    float* hT       = wsf + 512;
    float* p1       = wsf + 132096;
    float* p2       = wsf + 4326400;

    k1_gate_ffn1<<<dim3(512), dim3(256), 0, stream>>>(x, wg, bg, w1, bmask, gate0,
                                                      p1, out, counters);
    k2_gelu_score<<<dim3(257), dim3(128), 0, stream>>>(p1, b1, hT, bmask, gate0, gs,
                                                       out + (out_size - 1));
    k3_ffn2<<<dim3(8, 32), dim3(128), 0, stream>>>(w2, hT, p2, b2, gs, out, counters);
}

// Round 4
// 270.522 us; speedup vs baseline: 1.2026x; 1.2026x over previous
//
#include <hip/hip_runtime.h>
#include <math.h>

static constexpr int Nn = 512;
static constexpr int Dd = 1024;
static constexpr int Ee = 8;
static constexpr int Hh = 4096;
static constexpr float CAP = 4.0f;   // float(int(1.0 * B))
static constexpr float EPS = 1e-6f;

static constexpr int P2S = 32;   // ffn2 k-splits (depth 128)

// LESSON (round 3): device-fence + last-block-tail reduction cost ~+70us
// (k3 went to 139us, HBM 1.5%). Node boundaries are ~10us — never replace
// one with __threadfence-based cross-block sync here.
//
// ws layout (float offsets):
//   [0,256)             bmask (int, one per gate block; fully written -> no memset)
//   [256,288)           gate0
//   [320,352)           gs
//   [512,131584)        hT[32][4096]   (token-major)
//   [132096,1180672)    p2[32*32][1024]

// =====================================================================
// N1: blocks [0,256)  ffn1 FULL-K GEMM + bias + exact GELU -> hT
//                     (block = 16 h-cols, 1024 k, 32 tokens; no p1)
//     blocks [256,512) gating (8 tokens/block) + zero own dead out rows
// =====================================================================
__global__ __launch_bounds__(256) void n1_gate_ffn1(
    const float* __restrict__ x, const float* __restrict__ wg,
    const float* __restrict__ bg, const float* __restrict__ w1,
    const float* __restrict__ b1, int* __restrict__ bmask,
    float* __restrict__ gate0, float* __restrict__ hT,
    float* __restrict__ out)
{
    __shared__ float smem[8 * 1028 + 16];   // gate needs 32.96KB; ffn1 uses 12KB
    const int blk = blockIdx.x;
    const int tid = threadIdx.x;

    if (blk < 256) {
        // ---- ffn1 full-K: h-cols [hb, hb+16), all k, all 32 live tokens ----
        float* sX = smem;            // [64][32]  k-chunk of X^T
        float* sW = smem + 2048;     // [64][16]  k-chunk of W1
        const int hb = blk * 16;
        const int h  = tid & 15;           // h-col within block
        const int tp = tid >> 4;           // token-pair 0..15
        const int t0 = tid & 31, kq = tid >> 5;            // staging coords
        const int row0 = (t0 >> 3) * Nn + (t0 & 7);        // token t0 = b*8+n
        const int kwr  = tid >> 4;                         // W stage k-row base

        float4 xr0, xr1;
        float  wr[4];
        {   // prologue: load chunk 0
            const float* xp = x + (size_t)row0 * Dd;
            xr0 = *(const float4*)(xp + kq * 4);
            xr1 = *(const float4*)(xp + (kq + 8) * 4);
#pragma unroll
            for (int j = 0; j < 4; ++j)
                wr[j] = w1[(size_t)(kwr + j * 16) * Hh + hb + h];
        }
        {   // store chunk 0
            sX[(kq * 4 + 0) * 32 + t0] = xr0.x;
            sX[(kq * 4 + 1) * 32 + t0] = xr0.y;
            sX[(kq * 4 + 2) * 32 + t0] = xr0.z;
            sX[(kq * 4 + 3) * 32 + t0] = xr0.w;
            sX[((kq + 8) * 4 + 0) * 32 + t0] = xr1.x;
            sX[((kq + 8) * 4 + 1) * 32 + t0] = xr1.y;
            sX[((kq + 8) * 4 + 2) * 32 + t0] = xr1.z;
            sX[((kq + 8) * 4 + 3) * 32 + t0] = xr1.w;
#pragma unroll
            for (int j = 0; j < 4; ++j)
                sW[(kwr + j * 16) * 16 + h] = wr[j];
        }
        __syncthreads();

        const float b1v = b1[hb + h];
        float a0 = b1v, a1 = b1v;          // bias-first (matches old k2 order)

        for (int c = 0; c < 16; ++c) {
            float4 nx0, nx1;
            float  nw[4];
            if (c < 15) {                  // issue next-chunk global loads
                const int k0 = (c + 1) * 64;
                const float* xp = x + (size_t)row0 * Dd + k0;
                nx0 = *(const float4*)(xp + kq * 4);
                nx1 = *(const float4*)(xp + (kq + 8) * 4);
#pragma unroll
                for (int j = 0; j < 4; ++j)
                    nw[j] = w1[(size_t)(k0 + kwr + j * 16) * Hh + hb + h];
            }
            // inner: 64 k, 2 tokens  (W: 16-lane broadcast; X: 4-addr broadcast)
            const float* xp = sX + 2 * tp;
#pragma unroll
            for (int kk = 0; kk < 64; ++kk) {
                const float  w  = sW[kk * 16 + h];
                const float2 xv = *(const float2*)(xp + kk * 32);
                a0 = fmaf(xv.x, w, a0);
                a1 = fmaf(xv.y, w, a1);
            }
            if (c < 15) {
                __syncthreads();
                sX[(kq * 4 + 0) * 32 + t0] = nx0.x;
                sX[(kq * 4 + 1) * 32 + t0] = nx0.y;
                sX[(kq * 4 + 2) * 32 + t0] = nx0.z;
                sX[(kq * 4 + 3) * 32 + t0] = nx0.w;
                sX[((kq + 8) * 4 + 0) * 32 + t0] = nx1.x;
                sX[((kq + 8) * 4 + 1) * 32 + t0] = nx1.y;
                sX[((kq + 8) * 4 + 2) * 32 + t0] = nx1.z;
                sX[((kq + 8) * 4 + 3) * 32 + t0] = nx1.w;
#pragma unroll
                for (int j = 0; j < 4; ++j)
                    sW[((c + 1) * 64 ? (kwr + j * 16) : 0) * 16 + h] = nw[j];
                __syncthreads();
            }
        }
        const float cst = 0.70710678118654752440f;
        const float g0 = 0.5f * a0 * (1.f + erff(a0 * cst));
        const float g1 = 0.5f * a1 * (1.f + erff(a1 * cst));
        hT[(size_t)(2 * tp) * Hh + hb + h]     = g0;
        hT[(size_t)(2 * tp + 1) * Hh + hb + h] = g1;
    } else {
        // ---- gating + zeroing: block g handles tokens g*8 .. g*8+7 ----
        const int g = blk - 256;
        {   // zero this block's dead out rows (n >= 8)
            const float4 zero4 = make_float4(0.f, 0.f, 0.f, 0.f);
#pragma unroll
            for (int r = 0; r < 8; ++r) {
                const int tok = g * 8 + r;
                if ((tok & (Nn - 1)) >= 8)
                    *(float4*)(out + (size_t)tok * Dd + tid * 4) = zero4;
            }
        }
        for (int i = tid; i < Dd * Ee; i += 256)
            smem[(i & 7) * 1028 + (i >> 3)] = wg[i];       // wg[d][e] -> [e][d] padded
        int* bb = (int*)&smem[8224];
        __syncthreads();
        const int wave = tid >> 6, lane = tid & 63;
        for (int j = 0; j < 2; ++j) {
            const int sub = wave + 4 * j;                  // 0..7
            const int tok = g * 8 + sub;
            const float* xr = x + (size_t)tok * Dd;
            float acc[Ee];
#pragma unroll
            for (int e = 0; e < Ee; ++e) acc[e] = 0.f;
#pragma unroll
            for (int jj = 0; jj < 4; ++jj) {
                const int d0 = jj * 256 + lane * 4;
                float4 xv = *(const float4*)(xr + d0);
#pragma unroll
                for (int e = 0; e < Ee; ++e) {
                    float4 wv = *(const float4*)(&smem[e * 1028 + d0]);
                    acc[e] = fmaf(xv.x, wv.x, acc[e]);
                    acc[e] = fmaf(xv.y, wv.y, acc[e]);
                    acc[e] = fmaf(xv.z, wv.z, acc[e]);
                    acc[e] = fmaf(xv.w, wv.w, acc[e]);
                }
            }
#pragma unroll
            for (int e = 0; e < Ee; ++e) {
                float v = acc[e];
#pragma unroll
                for (int off = 32; off > 0; off >>= 1) v += __shfl_xor(v, off, 64);
                acc[e] = v + bg[e];
            }
            if (lane == 0) {
                int best = 0;
                float bv = acc[0];
#pragma unroll
                for (int e = 1; e < Ee; ++e)
                    if (acc[e] > bv) { bv = acc[e]; best = e; }   // strict > = jnp.argmax
                bb[sub] = 1 << best;
                const int n = tok & (Nn - 1);
                const int b = tok >> 9;
                if (n < 8) {
                    float m = acc[0];
#pragma unroll
                    for (int e = 1; e < Ee; ++e) m = fmaxf(m, acc[e]);
                    float s = 0.f;
#pragma unroll
                    for (int e = 0; e < Ee; ++e) s += expf(acc[e] - m);
                    gate0[b * 8 + n] = expf(acc[0] - m) / s;   // softmax prob of expert 0
                }
            }
        }
        __syncthreads();
        if (tid == 0) {
            int m = 0;
#pragma unroll
            for (int i = 0; i < 8; ++i) m |= bb[i];
            bmask[g] = m;
        }
    }
}

// =====================================================================
// N2: blocks [0,256)  ffn2 k-split GEMM (verbatim round-2 k3; dx=blk&7,
//                     ky=blk>>3)
//     block 256:      lane-parallel gate_scores + loss (verbatim)
// =====================================================================
__global__ __launch_bounds__(128) void n2_ffn2_score(
    const float* __restrict__ w2, const float* __restrict__ hT,
    float* __restrict__ p2, const int* __restrict__ bmask,
    const float* __restrict__ gate0, float* __restrict__ gs,
    float* __restrict__ loss_out)
{
    __shared__ float smem[128 * 32];     // [k][t]
    const int blk = blockIdx.x, tid = threadIdx.x;
    if (blk < 256) {
        const int dx = blk & 7, ky = blk >> 3;     // d-chunk, k-split
        {
            const int t = tid & 31, kq = tid >> 5;    // kq 0..3 (32 k each)
            const float* src = hT + (size_t)t * Hh + ky * 128 + kq * 32;
#pragma unroll
            for (int c = 0; c < 8; ++c) {
                float4 v = *(const float4*)(src + c * 4);
                smem[(kq * 32 + c * 4 + 0) * 32 + t] = v.x;
                smem[(kq * 32 + c * 4 + 1) * 32 + t] = v.y;
                smem[(kq * 32 + c * 4 + 2) * 32 + t] = v.z;
                smem[(kq * 32 + c * 4 + 3) * 32 + t] = v.w;
            }
        }
        __syncthreads();
        const int d = dx * 128 + tid;
        const int k0 = ky * 128;
        const float* wp = w2 + (size_t)k0 * Dd + d;   // expert 0: w2[h][d]
        float acc[32];
#pragma unroll
        for (int t = 0; t < 32; ++t) acc[t] = 0.f;
#pragma unroll
        for (int q = 0; q < 8; ++q) {
            float wbuf[16];
#pragma unroll
            for (int kk = 0; kk < 16; ++kk)
                wbuf[kk] = wp[(size_t)(q * 16 + kk) * Dd];
#pragma unroll
            for (int kk = 0; kk < 16; ++kk) {
                const float4* xrow = (const float4*)(smem + (q * 16 + kk) * 32);
                const float w = wbuf[kk];
#pragma unroll
                for (int t4 = 0; t4 < 8; ++t4) {
                    float4 xv = xrow[t4];
                    acc[t4 * 4 + 0] = fmaf(xv.x, w, acc[t4 * 4 + 0]);
                    acc[t4 * 4 + 1] = fmaf(xv.y, w, acc[t4 * 4 + 1]);
                    acc[t4 * 4 + 2] = fmaf(xv.z, w, acc[t4 * 4 + 2]);
                    acc[t4 * 4 + 3] = fmaf(xv.w, w, acc[t4 * 4 + 3]);
                }
            }
        }
        float* o = p2 + ((size_t)ky * 32) * Dd + d;
#pragma unroll
        for (int t = 0; t < 32; ++t) { *o = acc[t]; o += Dd; }
    } else if (tid < 64) {
        const int l = tid;
        int m0 = bmask[l], m1 = bmask[64 + l], m2 = bmask[128 + l], m3 = bmask[192 + l];
#pragma unroll
        for (int off = 32; off > 0; off >>= 1) {
            m0 |= __shfl_xor(m0, off, 64);
            m1 |= __shfl_xor(m1, off, 64);
            m2 |= __shfl_xor(m2, off, 64);
            m3 |= __shfl_xor(m3, off, 64);
        }
        float gm = 0.f;
        if (l < 32) {
            const int b = l >> 3, n = l & 7;
            const int sm = (b == 0) ? m0 : (b == 1) ? m1 : (b == 2) ? m2 : m3;
            if ((sm >> n) & 1) gm = gate0[l];
        }
        float den = gm + __shfl_xor(gm, 8, 64);
        den += __shfl_xor(den, 16, 64);
        float gsv = 0.f;
        if (l < 32) { gsv = gm / (den + EPS) * CAP; gs[l] = gsv; }
        float impn = gsv + __shfl_xor(gsv, 8, 64); impn += __shfl_xor(impn, 16, 64);
        float ldv = (gsv > 0.f) ? 1.f : 0.f;
        float ldn = ldv + __shfl_xor(ldv, 8, 64); ldn += __shfl_xor(ldn, 16, 64);
        float si = gsv, sl = ldv;
#pragma unroll
        for (int off = 32; off > 0; off >>= 1) {
            si += __shfl_xor(si, off, 64);
            sl += __shfl_xor(sl, off, 64);
        }
        const float M = (float)(Nn * Ee);
        const float mi = si / M, ml = sl / M;
        float di = (l < 8) ? (impn - mi) * (impn - mi) : 0.f;
        float dl = (l < 8) ? (ldn - ml) * (ldn - ml) : 0.f;
#pragma unroll
        for (int off = 32; off > 0; off >>= 1) {
            di += __shfl_xor(di, off, 64);
            dl += __shfl_xor(dl, off, 64);
        }
        if (l == 0) {
            di += (M - 8.f) * mi * mi;
            dl += (M - 8.f) * ml * ml;
            const float vi = di / (M - 1.f), vl = dl / (M - 1.f);
            *loss_out = vi / (mi * mi + 1e-10f) + vl / (ml * ml + 1e-10f);
        }
    }
}

// =====================================================================
// N3: reduce p2 + bias + gate scale for the 32 live rows. 64 blk x 128
// =====================================================================
__global__ __launch_bounds__(128) void n3_out(
    const float* __restrict__ p2, const float* __restrict__ b2,
    const float* __restrict__ gs, float* __restrict__ out)
{
    const int t = blockIdx.x >> 1;
    const int d4 = (blockIdx.x & 1) * 512 + threadIdx.x * 4;
    float4 a = make_float4(0.f, 0.f, 0.f, 0.f);
    const float* p = p2 + (size_t)t * Dd + d4;
#pragma unroll 8
    for (int s = 0; s < P2S; ++s) {
        float4 v = *(const float4*)p;
        p += (size_t)32 * Dd;
        a.x += v.x; a.y += v.y; a.z += v.z; a.w += v.w;
    }
    float4 bbv = *(const float4*)(b2 + d4);       // expert 0: b2[0][d]
    const float g = gs[t];
    const int b = t >> 3, n = t & 7;
    float4 o;
    o.x = g * (a.x + bbv.x);
    o.y = g * (a.y + bbv.y);
    o.z = g * (a.z + bbv.z);
    o.w = g * (a.w + bbv.w);
    *(float4*)(out + ((size_t)(b * Nn + n)) * Dd + d4) = o;
}

extern "C" void kernel_launch(void* const* d_in, const int* in_sizes, int n_in,
                              void* d_out, int out_size, void* d_ws, size_t ws_size,
                              hipStream_t stream) {
    const float* x  = (const float*)d_in[0];
    const float* wg = (const float*)d_in[1];
    const float* bg = (const float*)d_in[2];
    const float* w1 = (const float*)d_in[3];
    const float* b1 = (const float*)d_in[4];
    const float* w2 = (const float*)d_in[5];
    const float* b2 = (const float*)d_in[6];
    float* out = (float*)d_out;
    float* wsf = (float*)d_ws;

    int*   bmask = (int*)d_ws;
    float* gate0 = wsf + 256;
    float* gs    = wsf + 320;
    float* hT    = wsf + 512;
    float* p2    = wsf + 132096;

    n1_gate_ffn1<<<dim3(512), dim3(256), 0, stream>>>(x, wg, bg, w1, b1, bmask,
                                                      gate0, hT, out);
    n2_ffn2_score<<<dim3(257), dim3(128), 0, stream>>>(w2, hT, p2, bmask, gate0, gs,
                                                       out + (out_size - 1));
    n3_out<<<dim3(64), dim3(128), 0, stream>>>(p2, b2, gs, out);
}

// Round 5
// 261.273 us; speedup vs baseline: 1.2451x; 1.0354x over previous
//
#include <hip/hip_runtime.h>
#include <math.h>

static constexpr int Nn = 512;
static constexpr int Dd = 1024;
static constexpr int Ee = 8;
static constexpr int Hh = 4096;
static constexpr float CAP = 4.0f;   // float(int(1.0 * B))
static constexpr float EPS = 1e-6f;

static constexpr int P2S = 128;  // ffn2 k-splits (depth 32)

// LESSONS:
//  (r3) device-fence + last-block-tail reduction cost ~+70us. Node
//       boundaries are ~10us — never replace one with __threadfence sync.
//  (r4) dur_us ≈ 2x77us harness fills + sum(our kernels). ffn2 k-split
//       at 256blk x 128thr = 2 waves/CU ran 81us on ~6us of work: pure
//       latency exposure at 5% occupancy. Memory-latency kernels need
//       >=8 waves/CU here.
//
// ws layout (float offsets):
//   [0,256)             bmask (int, one per gate block; fully written -> no memset)
//   [256,288)           gate0
//   [320,352)           gs
//   [512,131584)        hT[32][4096]   (token-major)
//   [132096,4326400)    p2[128*32][1024]  (16MB)

// =====================================================================
// N1: blocks [0,256)  ffn1 FULL-K GEMM + bias + exact GELU -> hT
//                     (block = 16 h-cols, 1024 k, 32 tokens; no p1)
//     blocks [256,512) gating (8 tokens/block) + zero own dead out rows
// =====================================================================
__global__ __launch_bounds__(256) void n1_gate_ffn1(
    const float* __restrict__ x, const float* __restrict__ wg,
    const float* __restrict__ bg, const float* __restrict__ w1,
    const float* __restrict__ b1, int* __restrict__ bmask,
    float* __restrict__ gate0, float* __restrict__ hT,
    float* __restrict__ out)
{
    __shared__ float smem[8 * 1028 + 16];   // gate needs 32.96KB; ffn1 uses 12KB
    const int blk = blockIdx.x;
    const int tid = threadIdx.x;

    if (blk < 256) {
        // ---- ffn1 full-K: h-cols [hb, hb+16), all k, all 32 live tokens ----
        float* sX = smem;            // [64][32]  k-chunk of X^T
        float* sW = smem + 2048;     // [64][16]  k-chunk of W1
        const int hb = blk * 16;
        const int h  = tid & 15;           // h-col within block
        const int tp = tid >> 4;           // token-pair 0..15
        const int t0 = tid & 31, kq = tid >> 5;            // staging coords
        const int row0 = (t0 >> 3) * Nn + (t0 & 7);        // token t0 = b*8+n
        const int kwr  = tid >> 4;                         // W stage k-row base

        float4 xr0, xr1;
        float  wr[4];
        {   // prologue: load chunk 0
            const float* xp = x + (size_t)row0 * Dd;
            xr0 = *(const float4*)(xp + kq * 4);
            xr1 = *(const float4*)(xp + (kq + 8) * 4);
#pragma unroll
            for (int j = 0; j < 4; ++j)
                wr[j] = w1[(size_t)(kwr + j * 16) * Hh + hb + h];
        }
        {   // store chunk 0
            sX[(kq * 4 + 0) * 32 + t0] = xr0.x;
            sX[(kq * 4 + 1) * 32 + t0] = xr0.y;
            sX[(kq * 4 + 2) * 32 + t0] = xr0.z;
            sX[(kq * 4 + 3) * 32 + t0] = xr0.w;
            sX[((kq + 8) * 4 + 0) * 32 + t0] = xr1.x;
            sX[((kq + 8) * 4 + 1) * 32 + t0] = xr1.y;
            sX[((kq + 8) * 4 + 2) * 32 + t0] = xr1.z;
            sX[((kq + 8) * 4 + 3) * 32 + t0] = xr1.w;
#pragma unroll
            for (int j = 0; j < 4; ++j)
                sW[(kwr + j * 16) * 16 + h] = wr[j];
        }
        __syncthreads();

        const float b1v = b1[hb + h];
        float a0 = b1v, a1 = b1v;          // bias-first (matches old k2 order)

        for (int c = 0; c < 16; ++c) {
            float4 nx0, nx1;
            float  nw[4];
            if (c < 15) {                  // issue next-chunk global loads
                const int k0 = (c + 1) * 64;
                const float* xp = x + (size_t)row0 * Dd + k0;
                nx0 = *(const float4*)(xp + kq * 4);
                nx1 = *(const float4*)(xp + (kq + 8) * 4);
#pragma unroll
                for (int j = 0; j < 4; ++j)
                    nw[j] = w1[(size_t)(k0 + kwr + j * 16) * Hh + hb + h];
            }
            // inner: 64 k, 2 tokens  (W: 16-lane broadcast; X: 4-addr broadcast)
            const float* xp = sX + 2 * tp;
#pragma unroll
            for (int kk = 0; kk < 64; ++kk) {
                const float  w  = sW[kk * 16 + h];
                const float2 xv = *(const float2*)(xp + kk * 32);
                a0 = fmaf(xv.x, w, a0);
                a1 = fmaf(xv.y, w, a1);
            }
            if (c < 15) {
                __syncthreads();
                sX[(kq * 4 + 0) * 32 + t0] = nx0.x;
                sX[(kq * 4 + 1) * 32 + t0] = nx0.y;
                sX[(kq * 4 + 2) * 32 + t0] = nx0.z;
                sX[(kq * 4 + 3) * 32 + t0] = nx0.w;
                sX[((kq + 8) * 4 + 0) * 32 + t0] = nx1.x;
                sX[((kq + 8) * 4 + 1) * 32 + t0] = nx1.y;
                sX[((kq + 8) * 4 + 2) * 32 + t0] = nx1.z;
                sX[((kq + 8) * 4 + 3) * 32 + t0] = nx1.w;
#pragma unroll
                for (int j = 0; j < 4; ++j)
                    sW[(kwr + j * 16) * 16 + h] = nw[j];
                __syncthreads();
            }
        }
        const float cst = 0.70710678118654752440f;
        const float g0 = 0.5f * a0 * (1.f + erff(a0 * cst));
        const float g1 = 0.5f * a1 * (1.f + erff(a1 * cst));
        hT[(size_t)(2 * tp) * Hh + hb + h]     = g0;
        hT[(size_t)(2 * tp + 1) * Hh + hb + h] = g1;
    } else {
        // ---- gating + zeroing: block g handles tokens g*8 .. g*8+7 ----
        const int g = blk - 256;
        {   // zero this block's dead out rows (n >= 8)
            const float4 zero4 = make_float4(0.f, 0.f, 0.f, 0.f);
#pragma unroll
            for (int r = 0; r < 8; ++r) {
                const int tok = g * 8 + r;
                if ((tok & (Nn - 1)) >= 8)
                    *(float4*)(out + (size_t)tok * Dd + tid * 4) = zero4;
            }
        }
        for (int i = tid; i < Dd * Ee; i += 256)
            smem[(i & 7) * 1028 + (i >> 3)] = wg[i];       // wg[d][e] -> [e][d] padded
        int* bb = (int*)&smem[8224];
        __syncthreads();
        const int wave = tid >> 6, lane = tid & 63;
        for (int j = 0; j < 2; ++j) {
            const int sub = wave + 4 * j;                  // 0..7
            const int tok = g * 8 + sub;
            const float* xr = x + (size_t)tok * Dd;
            float acc[Ee];
#pragma unroll
            for (int e = 0; e < Ee; ++e) acc[e] = 0.f;
#pragma unroll
            for (int jj = 0; jj < 4; ++jj) {
                const int d0 = jj * 256 + lane * 4;
                float4 xv = *(const float4*)(xr + d0);
#pragma unroll
                for (int e = 0; e < Ee; ++e) {
                    float4 wv = *(const float4*)(&smem[e * 1028 + d0]);
                    acc[e] = fmaf(xv.x, wv.x, acc[e]);
                    acc[e] = fmaf(xv.y, wv.y, acc[e]);
                    acc[e] = fmaf(xv.z, wv.z, acc[e]);
                    acc[e] = fmaf(xv.w, wv.w, acc[e]);
                }
            }
#pragma unroll
            for (int e = 0; e < Ee; ++e) {
                float v = acc[e];
#pragma unroll
                for (int off = 32; off > 0; off >>= 1) v += __shfl_xor(v, off, 64);
                acc[e] = v + bg[e];
            }
            if (lane == 0) {
                int best = 0;
                float bv = acc[0];
#pragma unroll
                for (int e = 1; e < Ee; ++e)
                    if (acc[e] > bv) { bv = acc[e]; best = e; }   // strict > = jnp.argmax
                bb[sub] = 1 << best;
                const int n = tok & (Nn - 1);
                const int b = tok >> 9;
                if (n < 8) {
                    float m = acc[0];
#pragma unroll
                    for (int e = 1; e < Ee; ++e) m = fmaxf(m, acc[e]);
                    float s = 0.f;
#pragma unroll
                    for (int e = 0; e < Ee; ++e) s += expf(acc[e] - m);
                    gate0[b * 8 + n] = expf(acc[0] - m) / s;   // softmax prob of expert 0
                }
            }
        }
        __syncthreads();
        if (tid == 0) {
            int m = 0;
#pragma unroll
            for (int i = 0; i < 8; ++i) m |= bb[i];
            bmask[g] = m;
        }
    }
}

// =====================================================================
// N2: blocks [0,512)  ffn2 k-split GEMM, depth 32: dx=blk&3 (256 d),
//                     ky=blk>>2 (128 splits). 256 thr, ~8 waves/CU.
//     block 512:      lane-parallel gate_scores + loss (verbatim)
// =====================================================================
__global__ __launch_bounds__(256) void n2_ffn2_score(
    const float* __restrict__ w2, const float* __restrict__ hT,
    float* __restrict__ p2, const int* __restrict__ bmask,
    const float* __restrict__ gate0, float* __restrict__ gs,
    float* __restrict__ loss_out)
{
    __shared__ float smem[32 * 32];      // [k][t]
    const int blk = blockIdx.x, tid = threadIdx.x;
    if (blk < 512) {
        const int dx = blk & 3, ky = blk >> 2;    // d-chunk 256 wide, k-split 32 deep
        const int k0 = ky * 32;
        {   // stage hT[32 t][k0..k0+32) -> smem[k][t]
            const int t = tid >> 3, c = tid & 7;
            float4 v = *(const float4*)(hT + (size_t)t * Hh + k0 + c * 4);
            smem[(c * 4 + 0) * 32 + t] = v.x;
            smem[(c * 4 + 1) * 32 + t] = v.y;
            smem[(c * 4 + 2) * 32 + t] = v.z;
            smem[(c * 4 + 3) * 32 + t] = v.w;
        }
        __syncthreads();
        const int d = dx * 256 + tid;
        const float* wp = w2 + (size_t)k0 * Dd + d;   // expert 0: w2[h][d]
        float acc[32];
#pragma unroll
        for (int t = 0; t < 32; ++t) acc[t] = 0.f;
#pragma unroll
        for (int q = 0; q < 2; ++q) {
            float wbuf[16];
#pragma unroll
            for (int kk = 0; kk < 16; ++kk)
                wbuf[kk] = wp[(size_t)(q * 16 + kk) * Dd];
#pragma unroll
            for (int kk = 0; kk < 16; ++kk) {
                const float4* xrow = (const float4*)(smem + (q * 16 + kk) * 32);
                const float w = wbuf[kk];
#pragma unroll
                for (int t4 = 0; t4 < 8; ++t4) {
                    float4 xv = xrow[t4];
                    acc[t4 * 4 + 0] = fmaf(xv.x, w, acc[t4 * 4 + 0]);
                    acc[t4 * 4 + 1] = fmaf(xv.y, w, acc[t4 * 4 + 1]);
                    acc[t4 * 4 + 2] = fmaf(xv.z, w, acc[t4 * 4 + 2]);
                    acc[t4 * 4 + 3] = fmaf(xv.w, w, acc[t4 * 4 + 3]);
                }
            }
        }
        float* o = p2 + ((size_t)ky * 32) * Dd + d;
#pragma unroll
        for (int t = 0; t < 32; ++t) { *o = acc[t]; o += Dd; }
    } else if (tid < 64) {
        const int l = tid;
        int m0 = bmask[l], m1 = bmask[64 + l], m2 = bmask[128 + l], m3 = bmask[192 + l];
#pragma unroll
        for (int off = 32; off > 0; off >>= 1) {
            m0 |= __shfl_xor(m0, off, 64);
            m1 |= __shfl_xor(m1, off, 64);
            m2 |= __shfl_xor(m2, off, 64);
            m3 |= __shfl_xor(m3, off, 64);
        }
        float gm = 0.f;
        if (l < 32) {
            const int b = l >> 3, n = l & 7;
            const int sm = (b == 0) ? m0 : (b == 1) ? m1 : (b == 2) ? m2 : m3;
            if ((sm >> n) & 1) gm = gate0[l];
        }
        float den = gm + __shfl_xor(gm, 8, 64);
        den += __shfl_xor(den, 16, 64);
        float gsv = 0.f;
        if (l < 32) { gsv = gm / (den + EPS) * CAP; gs[l] = gsv; }
        float impn = gsv + __shfl_xor(gsv, 8, 64); impn += __shfl_xor(impn, 16, 64);
        float ldv = (gsv > 0.f) ? 1.f : 0.f;
        float ldn = ldv + __shfl_xor(ldv, 8, 64); ldn += __shfl_xor(ldn, 16, 64);
        float si = gsv, sl = ldv;
#pragma unroll
        for (int off = 32; off > 0; off >>= 1) {
            si += __shfl_xor(si, off, 64);
            sl += __shfl_xor(sl, off, 64);
        }
        const float M = (float)(Nn * Ee);
        const float mi = si / M, ml = sl / M;
        float di = (l < 8) ? (impn - mi) * (impn - mi) : 0.f;
        float dl = (l < 8) ? (ldn - ml) * (ldn - ml) : 0.f;
#pragma unroll
        for (int off = 32; off > 0; off >>= 1) {
            di += __shfl_xor(di, off, 64);
            dl += __shfl_xor(dl, off, 64);
        }
        if (l == 0) {
            di += (M - 8.f) * mi * mi;
            dl += (M - 8.f) * ml * ml;
            const float vi = di / (M - 1.f), vl = dl / (M - 1.f);
            *loss_out = vi / (mi * mi + 1e-10f) + vl / (ml * ml + 1e-10f);
        }
    }
}

// =====================================================================
// N3: reduce 128 p2 partials + bias + gate scale, 32 live rows.
//     64 blocks x 256 thr, float2/thread, unroll 16 for outstanding loads.
// =====================================================================
__global__ __launch_bounds__(256) void n3_out(
    const float* __restrict__ p2, const float* __restrict__ b2,
    const float* __restrict__ gs, float* __restrict__ out)
{
    const int t = blockIdx.x >> 1;
    const int d2 = (blockIdx.x & 1) * 512 + threadIdx.x * 2;
    float2 a = make_float2(0.f, 0.f);
    const float* p = p2 + (size_t)t * Dd + d2;
#pragma unroll 16
    for (int s = 0; s < P2S; ++s) {
        float2 v = *(const float2*)p;
        p += (size_t)32 * Dd;
        a.x += v.x; a.y += v.y;
    }
    float2 bbv = *(const float2*)(b2 + d2);       // expert 0: b2[0][d]
    const float g = gs[t];
    const int b = t >> 3, n = t & 7;
    float2 o;
    o.x = g * (a.x + bbv.x);
    o.y = g * (a.y + bbv.y);
    *(float2*)(out + ((size_t)(b * Nn + n)) * Dd + d2) = o;
}

extern "C" void kernel_launch(void* const* d_in, const int* in_sizes, int n_in,
                              void* d_out, int out_size, void* d_ws, size_t ws_size,
                              hipStream_t stream) {
    const float* x  = (const float*)d_in[0];
    const float* wg = (const float*)d_in[1];
    const float* bg = (const float*)d_in[2];
    const float* w1 = (const float*)d_in[3];
    const float* b1 = (const float*)d_in[4];
    const float* w2 = (const float*)d_in[5];
    const float* b2 = (const float*)d_in[6];
    float* out = (float*)d_out;
    float* wsf = (float*)d_ws;

    int*   bmask = (int*)d_ws;
    float* gate0 = wsf + 256;
    float* gs    = wsf + 320;
    float* hT    = wsf + 512;
    float* p2    = wsf + 132096;

    n1_gate_ffn1<<<dim3(512), dim3(256), 0, stream>>>(x, wg, bg, w1, b1, bmask,
                                                      gate0, hT, out);
    n2_ffn2_score<<<dim3(513), dim3(256), 0, stream>>>(w2, hT, p2, bmask, gate0, gs,
                                                       out + (out_size - 1));
    n3_out<<<dim3(64), dim3(256), 0, stream>>>(p2, b2, gs, out);
}

// Round 6
// 255.159 us; speedup vs baseline: 1.2750x; 1.0240x over previous
//
#include <hip/hip_runtime.h>
#include <math.h>

static constexpr int Nn = 512;
static constexpr int Dd = 1024;
static constexpr int Ee = 8;
static constexpr int Hh = 4096;
static constexpr float CAP = 4.0f;   // float(int(1.0 * B))
static constexpr float EPS = 1e-6f;

static constexpr int P1S = 32;   // ffn1 k-splits (depth 32)
static constexpr int P2S = 128;  // ffn2 k-splits (depth 32)

// LESSONS:
//  (r3) device-fence + last-block-tail reduction cost ~+70us. Node
//       boundaries are ~5-10us — never replace one with __threadfence sync.
//  (r4) dur_us ≈ 2x77us harness fills + sum(our kernels).
//  (r5) ffn2 at 81us was NOT fixed by 4x occupancy (81->~70): scalar
//       4KB-strided w2 loads + vmcnt(0)-drained 16-batches + scalar
//       stores are the suspect. This round: float4 streams both ways.
//
// ws layout (float offsets):
//   [0,256)             bmask (int, one per gate block; fully written -> no memset)
//   [256,288)           gate0
//   [320,352)           gs
//   [512,131584)        hT[32][4096]   (token-major)
//   [132096,4326400)    p1[32*32][4096]   (16MB)
//   [4326400,8520704)   p2[128*32][1024]  (16MB)

// =====================================================================
// N1: blocks [0,256)  ffn1 k-split GEMM (r2-proven structure)
//     blocks [256,512) gating (8 tokens/block) + zero own dead out rows
// =====================================================================
__global__ __launch_bounds__(256) void n1_gate_ffn1(
    const float* __restrict__ x, const float* __restrict__ wg,
    const float* __restrict__ bg, const float* __restrict__ w1,
    int* __restrict__ bmask, float* __restrict__ gate0,
    float* __restrict__ p1, float* __restrict__ out)
{
    __shared__ float smem[8 * 1028 + 16];   // gate needs 32.96KB; ffn1 uses 4KB
    const int blk = blockIdx.x;
    const int tid = threadIdx.x;

    if (blk < 256) {
        // ---- ffn1 partial GEMM: h-chunk hc (512 wide), k-chunk ks (32 deep) ----
        const int hc = blk & 7, ks = blk >> 3, k0 = ks * 32;
        {   // stage x[32 live tokens][k0..k0+32) -> smem as [k][t]
            const int t = tid >> 3, q = tid & 7;
            const int row = (t >> 3) * Nn + (t & 7);       // token t = b*8+n
            float4 v = *(const float4*)(x + (size_t)row * Dd + k0 + q * 4);
            smem[(q * 4 + 0) * 32 + t] = v.x;
            smem[(q * 4 + 1) * 32 + t] = v.y;
            smem[(q * 4 + 2) * 32 + t] = v.z;
            smem[(q * 4 + 3) * 32 + t] = v.w;
        }
        __syncthreads();
        const int h = hc * 512 + tid * 2;
        const float* wp = w1 + (size_t)k0 * Hh + h;        // expert 0: w1[d][h]
        float2 acc[32];
#pragma unroll
        for (int t = 0; t < 32; ++t) acc[t] = make_float2(0.f, 0.f);
#pragma unroll
        for (int half = 0; half < 2; ++half) {
            float2 wbuf[16];
#pragma unroll
            for (int kk = 0; kk < 16; ++kk)
                wbuf[kk] = *(const float2*)(wp + (size_t)(half * 16 + kk) * Hh);
#pragma unroll
            for (int kk = 0; kk < 16; ++kk) {
                const float4* xrow = (const float4*)(smem + (half * 16 + kk) * 32);
                const float2 w = wbuf[kk];
#pragma unroll
                for (int t4 = 0; t4 < 8; ++t4) {
                    float4 xv = xrow[t4];
                    acc[t4 * 4 + 0].x = fmaf(xv.x, w.x, acc[t4 * 4 + 0].x);
                    acc[t4 * 4 + 0].y = fmaf(xv.x, w.y, acc[t4 * 4 + 0].y);
                    acc[t4 * 4 + 1].x = fmaf(xv.y, w.x, acc[t4 * 4 + 1].x);
                    acc[t4 * 4 + 1].y = fmaf(xv.y, w.y, acc[t4 * 4 + 1].y);
                    acc[t4 * 4 + 2].x = fmaf(xv.z, w.x, acc[t4 * 4 + 2].x);
                    acc[t4 * 4 + 2].y = fmaf(xv.z, w.y, acc[t4 * 4 + 2].y);
                    acc[t4 * 4 + 3].x = fmaf(xv.w, w.x, acc[t4 * 4 + 3].x);
                    acc[t4 * 4 + 3].y = fmaf(xv.w, w.y, acc[t4 * 4 + 3].y);
                }
            }
        }
        float* o = p1 + ((size_t)ks * 32) * Hh + h;
#pragma unroll
        for (int t = 0; t < 32; ++t) { *(float2*)o = acc[t]; o += Hh; }
    } else {
        // ---- gating + zeroing: block g handles tokens g*8 .. g*8+7 ----
        const int g = blk - 256;
        {   // zero this block's dead out rows (n >= 8)
            const float4 zero4 = make_float4(0.f, 0.f, 0.f, 0.f);
#pragma unroll
            for (int r = 0; r < 8; ++r) {
                const int tok = g * 8 + r;
                if ((tok & (Nn - 1)) >= 8)
                    *(float4*)(out + (size_t)tok * Dd + tid * 4) = zero4;
            }
        }
        for (int i = tid; i < Dd * Ee; i += 256)
            smem[(i & 7) * 1028 + (i >> 3)] = wg[i];       // wg[d][e] -> [e][d] padded
        int* bb = (int*)&smem[8224];
        __syncthreads();
        const int wave = tid >> 6, lane = tid & 63;
        for (int j = 0; j < 2; ++j) {
            const int sub = wave + 4 * j;                  // 0..7
            const int tok = g * 8 + sub;
            const float* xr = x + (size_t)tok * Dd;
            float acc[Ee];
#pragma unroll
            for (int e = 0; e < Ee; ++e) acc[e] = 0.f;
#pragma unroll
            for (int jj = 0; jj < 4; ++jj) {
                const int d0 = jj * 256 + lane * 4;
                float4 xv = *(const float4*)(xr + d0);
#pragma unroll
                for (int e = 0; e < Ee; ++e) {
                    float4 wv = *(const float4*)(&smem[e * 1028 + d0]);
                    acc[e] = fmaf(xv.x, wv.x, acc[e]);
                    acc[e] = fmaf(xv.y, wv.y, acc[e]);
                    acc[e] = fmaf(xv.z, wv.z, acc[e]);
                    acc[e] = fmaf(xv.w, wv.w, acc[e]);
                }
            }
#pragma unroll
            for (int e = 0; e < Ee; ++e) {
                float v = acc[e];
#pragma unroll
                for (int off = 32; off > 0; off >>= 1) v += __shfl_xor(v, off, 64);
                acc[e] = v + bg[e];
            }
            if (lane == 0) {
                int best = 0;
                float bv = acc[0];
#pragma unroll
                for (int e = 1; e < Ee; ++e)
                    if (acc[e] > bv) { bv = acc[e]; best = e; }   // strict > = jnp.argmax
                bb[sub] = 1 << best;
                const int n = tok & (Nn - 1);
                const int b = tok >> 9;
                if (n < 8) {
                    float m = acc[0];
#pragma unroll
                    for (int e = 1; e < Ee; ++e) m = fmaxf(m, acc[e]);
                    float s = 0.f;
#pragma unroll
                    for (int e = 0; e < Ee; ++e) s += expf(acc[e] - m);
                    gate0[b * 8 + n] = expf(acc[0] - m) / s;   // softmax prob of expert 0
                }
            }
        }
        __syncthreads();
        if (tid == 0) {
            int m = 0;
#pragma unroll
            for (int i = 0; i < 8; ++i) m |= bb[i];
            bmask[g] = m;
        }
    }
}

// =====================================================================
// N2: blocks [0,256) reduce p1 + bias + exact GELU -> hT[t][hh]
//     block 256: lane-parallel gate_scores + loss
// =====================================================================
__global__ __launch_bounds__(128) void n2_gelu_score(
    const float* __restrict__ p1, const float* __restrict__ b1,
    float* __restrict__ hT, const int* __restrict__ bmask,
    const float* __restrict__ gate0, float* __restrict__ gs,
    float* __restrict__ loss_out)
{
    const int blk = blockIdx.x, tid = threadIdx.x;
    if (blk < 256) {
        const int idx = blk * 128 + tid;              // 0..32767 (float4 granularity)
        const int hh0 = (idx << 2) & (Hh - 1);
        const int t = idx >> 10;
        float4 s = *(const float4*)(b1 + hh0);        // expert 0: b1[0][hh]
#pragma unroll
        for (int q = 0; q < P1S; ++q) {
            float4 v = *(const float4*)(p1 + ((size_t)(q * 32 + t)) * Hh + hh0);
            s.x += v.x; s.y += v.y; s.z += v.z; s.w += v.w;
        }
        const float c = 0.70710678118654752440f;
        float4 r;
        r.x = 0.5f * s.x * (1.f + erff(s.x * c));
        r.y = 0.5f * s.y * (1.f + erff(s.y * c));
        r.z = 0.5f * s.z * (1.f + erff(s.z * c));
        r.w = 0.5f * s.w * (1.f + erff(s.w * c));
        *(float4*)(hT + (size_t)t * Hh + hh0) = r;    // coalesced, t-major
    } else if (tid < 64) {
        const int l = tid;
        int m0 = bmask[l], m1 = bmask[64 + l], m2 = bmask[128 + l], m3 = bmask[192 + l];
#pragma unroll
        for (int off = 32; off > 0; off >>= 1) {
            m0 |= __shfl_xor(m0, off, 64);
            m1 |= __shfl_xor(m1, off, 64);
            m2 |= __shfl_xor(m2, off, 64);
            m3 |= __shfl_xor(m3, off, 64);
        }
        float gm = 0.f;
        if (l < 32) {
            const int b = l >> 3, n = l & 7;
            const int sm = (b == 0) ? m0 : (b == 1) ? m1 : (b == 2) ? m2 : m3;
            if ((sm >> n) & 1) gm = gate0[l];
        }
        float den = gm + __shfl_xor(gm, 8, 64);
        den += __shfl_xor(den, 16, 64);
        float gsv = 0.f;
        if (l < 32) { gsv = gm / (den + EPS) * CAP; gs[l] = gsv; }
        float impn = gsv + __shfl_xor(gsv, 8, 64); impn += __shfl_xor(impn, 16, 64);
        float ldv = (gsv > 0.f) ? 1.f : 0.f;
        float ldn = ldv + __shfl_xor(ldv, 8, 64); ldn += __shfl_xor(ldn, 16, 64);
        float si = gsv, sl = ldv;
#pragma unroll
        for (int off = 32; off > 0; off >>= 1) {
            si += __shfl_xor(si, off, 64);
            sl += __shfl_xor(sl, off, 64);
        }
        const float M = (float)(Nn * Ee);
        const float mi = si / M, ml = sl / M;
        float di = (l < 8) ? (impn - mi) * (impn - mi) : 0.f;
        float dl = (l < 8) ? (ldn - ml) * (ldn - ml) : 0.f;
#pragma unroll
        for (int off = 32; off > 0; off >>= 1) {
            di += __shfl_xor(di, off, 64);
            dl += __shfl_xor(dl, off, 64);
        }
        if (l == 0) {
            di += (M - 8.f) * mi * mi;
            dl += (M - 8.f) * ml * ml;
            const float vi = di / (M - 1.f), vl = dl / (M - 1.f);
            *loss_out = vi / (mi * mi + 1e-10f) + vl / (ml * ml + 1e-10f);
        }
    }
}

// =====================================================================
// N3: ffn2 GEMM, vectorized. 512 blocks (dx=blk&3: 256 d; ky=blk>>2:
//     128 k-splits of 32), 256 thr. Thread = 4 consecutive d (float4 w2
//     loads, 1KB/wave) x 8 tokens (32 acc). float4 p2 stores (1KB/wave).
// =====================================================================
__global__ __launch_bounds__(256) void n3_ffn2(
    const float* __restrict__ w2, const float* __restrict__ hT,
    float* __restrict__ p2)
{
    __shared__ float smem[32 * 32];      // [k][t]
    const int tid = threadIdx.x;
    const int dx = blockIdx.x & 3, ky = blockIdx.x >> 2;
    const int k0 = ky * 32;
    {   // stage hT[32 t][k0..k0+32) -> smem[k][t]
        const int t = tid >> 3, c = tid & 7;
        float4 v = *(const float4*)(hT + (size_t)t * Hh + k0 + c * 4);
        smem[(c * 4 + 0) * 32 + t] = v.x;
        smem[(c * 4 + 1) * 32 + t] = v.y;
        smem[(c * 4 + 2) * 32 + t] = v.z;
        smem[(c * 4 + 3) * 32 + t] = v.w;
    }
    __syncthreads();
    const int did = tid & 63;            // wave-contiguous d
    const int tg  = tid >> 6;            // token-group 0..3 (8 tokens)
    const int d   = dx * 256 + did * 4;
    const float* wp = w2 + (size_t)k0 * Dd + d;   // expert 0: w2[h][d]
    float4 acc[8];
#pragma unroll
    for (int tt = 0; tt < 8; ++tt) acc[tt] = make_float4(0.f, 0.f, 0.f, 0.f);
#pragma unroll
    for (int bq = 0; bq < 4; ++bq) {
        float4 wbuf[8];
#pragma unroll
        for (int kk = 0; kk < 8; ++kk)
            wbuf[kk] = *(const float4*)(wp + (size_t)(bq * 8 + kk) * Dd);
#pragma unroll
        for (int kk = 0; kk < 8; ++kk) {
            const float4 w4 = wbuf[kk];
            const float* xr = smem + (bq * 8 + kk) * 32 + tg * 8;
            const float4 x0 = *(const float4*)xr;
            const float4 x1 = *(const float4*)(xr + 4);
            acc[0].x = fmaf(x0.x, w4.x, acc[0].x); acc[0].y = fmaf(x0.x, w4.y, acc[0].y);
            acc[0].z = fmaf(x0.x, w4.z, acc[0].z); acc[0].w = fmaf(x0.x, w4.w, acc[0].w);
            acc[1].x = fmaf(x0.y, w4.x, acc[1].x); acc[1].y = fmaf(x0.y, w4.y, acc[1].y);
            acc[1].z = fmaf(x0.y, w4.z, acc[1].z); acc[1].w = fmaf(x0.y, w4.w, acc[1].w);
            acc[2].x = fmaf(x0.z, w4.x, acc[2].x); acc[2].y = fmaf(x0.z, w4.y, acc[2].y);
            acc[2].z = fmaf(x0.z, w4.z, acc[2].z); acc[2].w = fmaf(x0.z, w4.w, acc[2].w);
            acc[3].x = fmaf(x0.w, w4.x, acc[3].x); acc[3].y = fmaf(x0.w, w4.y, acc[3].y);
            acc[3].z = fmaf(x0.w, w4.z, acc[3].z); acc[3].w = fmaf(x0.w, w4.w, acc[3].w);
            acc[4].x = fmaf(x1.x, w4.x, acc[4].x); acc[4].y = fmaf(x1.x, w4.y, acc[4].y);
            acc[4].z = fmaf(x1.x, w4.z, acc[4].z); acc[4].w = fmaf(x1.x, w4.w, acc[4].w);
            acc[5].x = fmaf(x1.y, w4.x, acc[5].x); acc[5].y = fmaf(x1.y, w4.y, acc[5].y);
            acc[5].z = fmaf(x1.y, w4.z, acc[5].z); acc[5].w = fmaf(x1.y, w4.w, acc[5].w);
            acc[6].x = fmaf(x1.z, w4.x, acc[6].x); acc[6].y = fmaf(x1.z, w4.y, acc[6].y);
            acc[6].z = fmaf(x1.z, w4.z, acc[6].z); acc[6].w = fmaf(x1.z, w4.w, acc[6].w);
            acc[7].x = fmaf(x1.w, w4.x, acc[7].x); acc[7].y = fmaf(x1.w, w4.y, acc[7].y);
            acc[7].z = fmaf(x1.w, w4.z, acc[7].z); acc[7].w = fmaf(x1.w, w4.w, acc[7].w);
        }
    }
#pragma unroll
    for (int tt = 0; tt < 8; ++tt)
        *(float4*)(p2 + ((size_t)(ky * 32 + tg * 8 + tt)) * Dd + d) = acc[tt];
}

// =====================================================================
// N4: reduce 128 p2 partials + bias + gate scale, 32 live rows.
//     64 blocks x 256 thr, float2/thread, unroll 16.
// =====================================================================
__global__ __launch_bounds__(256) void n4_out(
    const float* __restrict__ p2, const float* __restrict__ b2,
    const float* __restrict__ gs, float* __restrict__ out)
{
    const int t = blockIdx.x >> 1;
    const int d2 = (blockIdx.x & 1) * 512 + threadIdx.x * 2;
    float2 a = make_float2(0.f, 0.f);
    const float* p = p2 + (size_t)t * Dd + d2;
#pragma unroll 16
    for (int s = 0; s < P2S; ++s) {
        float2 v = *(const float2*)p;
        p += (size_t)32 * Dd;
        a.x += v.x; a.y += v.y;
    }
    float2 bbv = *(const float2*)(b2 + d2);       // expert 0: b2[0][d]
    const float g = gs[t];
    const int b = t >> 3, n = t & 7;
    float2 o;
    o.x = g * (a.x + bbv.x);
    o.y = g * (a.y + bbv.y);
    *(float2*)(out + ((size_t)(b * Nn + n)) * Dd + d2) = o;
}

extern "C" void kernel_launch(void* const* d_in, const int* in_sizes, int n_in,
                              void* d_out, int out_size, void* d_ws, size_t ws_size,
                              hipStream_t stream) {
    const float* x  = (const float*)d_in[0];
    const float* wg = (const float*)d_in[1];
    const float* bg = (const float*)d_in[2];
    const float* w1 = (const float*)d_in[3];
    const float* b1 = (const float*)d_in[4];
    const float* w2 = (const float*)d_in[5];
    const float* b2 = (const float*)d_in[6];
    float* out = (float*)d_out;
    float* wsf = (float*)d_ws;

    int*   bmask = (int*)d_ws;
    float* gate0 = wsf + 256;
    float* gs    = wsf + 320;
    float* hT    = wsf + 512;
    float* p1    = wsf + 132096;
    float* p2    = wsf + 4326400;

    n1_gate_ffn1<<<dim3(512), dim3(256), 0, stream>>>(x, wg, bg, w1, bmask, gate0,
                                                      p1, out);
    n2_gelu_score<<<dim3(257), dim3(128), 0, stream>>>(p1, b1, hT, bmask, gate0, gs,
                                                       out + (out_size - 1));
    n3_ffn2<<<dim3(512), dim3(256), 0, stream>>>(w2, hT, p2);
    n4_out<<<dim3(64), dim3(256), 0, stream>>>(p2, b2, gs, out);
}